// Round 12
// baseline (250.251 us; speedup 1.0000x reference)
//
#include <hip/hip_runtime.h>
#include <hip/hip_bf16.h>
#include <stdint.h>

typedef __bf16 bf16x8 __attribute__((ext_vector_type(8)));
typedef __bf16 bf16x4 __attribute__((ext_vector_type(4)));
typedef float  f32x4  __attribute__((ext_vector_type(4)));
typedef float  f32x16 __attribute__((ext_vector_type(16)));

__device__ __forceinline__ void gl_lds16(const void* g, void* l) {
  __builtin_amdgcn_global_load_lds(
      (const __attribute__((address_space(1))) unsigned int*)g,
      (__attribute__((address_space(3))) unsigned int*)l, 16, 0, 0);
}

__device__ __forceinline__ unsigned pk2(float a, float b) {
  union { __bf16 h[2]; unsigned u; } z;
  z.h[0] = (__bf16)a; z.h[1] = (__bf16)b;
  return z.u;
}

// ---------------------------------------------------------------------------
// Merged prep: X fp32->bf16 convert (blocks 0..4095), W_qkv transpose-convert
// (4096..4863), W_proj transpose-convert (4864..5119).
// ---------------------------------------------------------------------------
__global__ __launch_bounds__(256) void prep_kernel(
    const float* __restrict__ x, __bf16* __restrict__ Xb,
    const float* __restrict__ w_qkv, __bf16* __restrict__ wt_qkv,
    const float* __restrict__ w_proj, __bf16* __restrict__ wt_proj) {
  __shared__ __bf16 tile[64][65];
  const int bid = blockIdx.x, t = threadIdx.x;
  if (bid < 4096) {
    const size_t i = ((size_t)bid * 256 + t) * 8;
    float4 v0 = *reinterpret_cast<const float4*>(x + i);
    float4 v1 = *reinterpret_cast<const float4*>(x + i + 4);
    bf16x8 o;
    o[0] = (__bf16)v0.x; o[1] = (__bf16)v0.y; o[2] = (__bf16)v0.z; o[3] = (__bf16)v0.w;
    o[4] = (__bf16)v1.x; o[5] = (__bf16)v1.y; o[6] = (__bf16)v1.z; o[7] = (__bf16)v1.w;
    *reinterpret_cast<bf16x8*>(Xb + i) = o;
    return;
  }
  const float* src; __bf16* dst; int K, N, bx, by;
  if (bid < 4864) {
    int idx = bid - 4096;
    src = w_qkv; dst = wt_qkv; K = 1024; N = 3072;
    bx = idx % 48; by = idx / 48;
  } else {
    int idx = bid - 4864;
    src = w_proj; dst = wt_proj; K = 1024; N = 1024;
    bx = idx & 15; by = idx >> 4;
  }
  const int n0 = bx * 64, k0 = by * 64;
#pragma unroll
  for (int e = 0; e < 16; ++e) {
    int idx = e * 256 + t;
    int kk = idx >> 6, nn = idx & 63;
    tile[nn][kk] = (__bf16)src[(size_t)(k0 + kk) * N + n0 + nn];
  }
  __syncthreads();
#pragma unroll
  for (int e = 0; e < 16; ++e) {
    int idx = e * 256 + t;
    int nn = idx >> 6, kk = idx & 63;
    dst[(size_t)(n0 + nn) * K + k0 + kk] = tile[nn][kk];
  }
}

// ---------------------------------------------------------------------------
// R8 triple-buffered counted-vmcnt GEMM core (measured best: qkv 68 us).
// BM=128, BN=NFRAG*64, BK=32, 256 thr = 4 waves.
// ---------------------------------------------------------------------------
template <int NFRAG>
__device__ __forceinline__ void gemm_core_1024(
    const __bf16* __restrict__ Ag, const __bf16* __restrict__ Bg,
    int m0, int n0, __bf16* lds, f32x4 (&acc)[8][NFRAG]) {
  constexpr int BUFSZ = 4096 + NFRAG * 2048;
  const int tid = threadIdx.x;
  const int wv = tid >> 6, l = tid & 63, g = l >> 4, lr = l & 15;
  const int sswL = (lr & 3) ^ ((lr >> 2) & 3);

  int arow[2], acol[2], brow[NFRAG], bcol[NFRAG];
#pragma unroll
  for (int e = 0; e < 2; ++e) {
    int c = e * 256 + tid, row = c >> 2, slot = c & 3;
    arow[e] = row;
    acol[e] = (slot ^ ((row & 3) ^ ((row >> 2) & 3))) * 8;
  }
#pragma unroll
  for (int e = 0; e < NFRAG; ++e) {
    int c = e * 256 + tid, row = c >> 2, slot = c & 3;
    brow[e] = row;
    bcol[e] = (slot ^ ((row & 3) ^ ((row >> 2) & 3))) * 8;
  }

  auto STAGE = [&](int bufb, int t) {
    const int kb = t * 32;
#pragma unroll
    for (int e = 0; e < 2; ++e)
      gl_lds16(Ag + (size_t)(m0 + arow[e]) * 1024 + kb + acol[e],
               lds + bufb + (e * 256 + wv * 64) * 8);
#pragma unroll
    for (int e = 0; e < NFRAG; ++e)
      gl_lds16(Bg + (size_t)(n0 + brow[e]) * 1024 + kb + bcol[e],
               lds + bufb + 4096 + (e * 256 + wv * 64) * 8);
  };

  int cur = 0, nx = BUFSZ, nn = 2 * BUFSZ;
  STAGE(cur, 0);
  STAGE(nx, 1);

#pragma unroll 1
  for (int t = 0; t < 32; ++t) {
    if (t < 31) {
      if constexpr (NFRAG == 3) asm volatile("s_waitcnt vmcnt(5)" ::: "memory");
      else                      asm volatile("s_waitcnt vmcnt(4)" ::: "memory");
    } else {
      asm volatile("s_waitcnt vmcnt(0)" ::: "memory");
    }
    __builtin_amdgcn_s_barrier();
    __builtin_amdgcn_sched_barrier(0);
    if (t + 2 < 32) STAGE(nn, t + 2);

    const char* Ab = (const char*)(lds + cur);
    const char* Bb = (const char*)(lds + cur + 4096);
    bf16x8 a[8], b[NFRAG];
#pragma unroll
    for (int mf = 0; mf < 8; ++mf)
      a[mf] = *reinterpret_cast<const bf16x8*>(
          Ab + (mf * 16 + lr) * 64 + ((g ^ sswL) << 4));
#pragma unroll
    for (int nf = 0; nf < NFRAG; ++nf)
      b[nf] = *reinterpret_cast<const bf16x8*>(
          Bb + (wv * NFRAG * 16 + nf * 16 + lr) * 64 + ((g ^ sswL) << 4));
    __builtin_amdgcn_s_setprio(1);
#pragma unroll
    for (int mf = 0; mf < 8; ++mf)
#pragma unroll
      for (int nf = 0; nf < NFRAG; ++nf)
        acc[mf][nf] = __builtin_amdgcn_mfma_f32_16x16x32_bf16(
            a[mf], b[nf], acc[mf][nf], 0, 0, 0);
    __builtin_amdgcn_s_setprio(0);

    int tmp = cur; cur = nx; nx = nn; nn = tmp;
  }
}

// ---------------------------------------------------------------------------
// QKV GEMM (R8 config): grid 1024 = 64 rb x 16 cb, BM=128 BN=192.
// ---------------------------------------------------------------------------
__global__ __launch_bounds__(256, 2) void qkv_gemm(
    const __bf16* __restrict__ Xb, const __bf16* __restrict__ WT,
    __bf16* __restrict__ Qb, __bf16* __restrict__ Kb, __bf16* __restrict__ Vb) {
  __shared__ __bf16 lds[30720];
  const int lin = blockIdx.x;
  const int sw = (lin & 7) * 128 + (lin >> 3);  // T1 bijective (1024 % 8 == 0)
  const int rb = sw >> 4, cb = sw & 15;
  const int m0 = rb * 128, n0 = cb * 192;

  f32x4 acc[8][3] = {};
  gemm_core_1024<3>(Xb, WT, m0, n0, lds, acc);

  const int tid = threadIdx.x, wv = tid >> 6, l = tid & 63, g = l >> 4, lr = l & 15;
#pragma unroll
  for (int mf = 0; mf < 8; ++mf)
#pragma unroll
    for (int nf = 0; nf < 3; ++nf) {
      int m_ = m0 + mf * 16 + g * 4;
      int nb = n0 + wv * 48 + nf * 16;
      int which = nb >> 10, hc = nb & 1023;
      int hh = hc >> 6, dk0 = hc & 63;
      int bbv = m_ >> 11, tt = m_ & 2047;
      if (which == 2) {
        bf16x4 vk;
        vk[0] = (__bf16)acc[mf][nf][0]; vk[1] = (__bf16)acc[mf][nf][1];
        vk[2] = (__bf16)acc[mf][nf][2]; vk[3] = (__bf16)acc[mf][nf][3];
        *reinterpret_cast<bf16x4*>(
            &Vb[((size_t)(bbv * 16 + hh) * 64 + dk0 + lr) * 2048 + tt]) = vk;
      } else if (which == 0) {
#pragma unroll
        for (int j = 0; j < 4; ++j)
          Qb[(((size_t)(bbv * 16 + hh)) * 2048 + tt + j) * 64 + dk0 + lr] =
              (__bf16)(acc[mf][nf][j] * 0.18033688f);  // 0.125*log2(e)
      } else {
#pragma unroll
        for (int j = 0; j < 4; ++j)
          Kb[(((size_t)(bbv * 16 + hh)) * 2048 + tt + j) * 64 + dk0 + lr] =
              (__bf16)acc[mf][nf][j];
      }
    }
}

// ---------------------------------------------------------------------------
// Proj GEMM (R8 config): grid 512 = 64 rb x 8 cb, BM=128 BN=128.
// ---------------------------------------------------------------------------
__global__ __launch_bounds__(256, 2) void proj_gemm(
    const __bf16* __restrict__ A, const __bf16* __restrict__ WT,
    float* __restrict__ Out) {
  __shared__ __bf16 lds[24576];
  const int lin = blockIdx.x;
  const int sw = (lin & 7) * 64 + (lin >> 3);   // T1 bijective (512 % 8 == 0)
  const int rb = sw >> 3, cb = sw & 7;
  const int m0 = rb * 128, n0 = cb * 128;

  f32x4 acc[8][2] = {};
  gemm_core_1024<2>(A, WT, m0, n0, lds, acc);

  const int tid = threadIdx.x, wv = tid >> 6, l = tid & 63, g = l >> 4, lr = l & 15;
#pragma unroll
  for (int mf = 0; mf < 8; ++mf)
#pragma unroll
    for (int nf = 0; nf < 2; ++nf) {
      int m_ = m0 + mf * 16 + g * 4;
      int n  = n0 + wv * 32 + nf * 16 + lr;
#pragma unroll
      for (int j = 0; j < 4; ++j)
        Out[(size_t)(m_ + j) * 1024 + n] = acc[mf][nf][j];
    }
}

// ---------------------------------------------------------------------------
// Causal flash attention, 32x32 MFMA, fully in-register P (shfl_xor exchange).
// Block = 4 waves x 32 q-rows = 128 q-rows; J paired with 15-J -> 36 KV iters.
// Grid 512 (2 blocks/CU). S^T = mfma(K, Q): lane holds P[q = lane&31][32 kv].
// PV B-frags built in-register: pack pairs to bf16, one shfl_xor(32) per word.
// Fixed-offset exp2 softmax (no max tracking); lsum lane-local.
// C/D layout (verified): col = lane&31, row = (reg&3)+8*(reg>>2)+4*(lane>>5).
// A/B input layout (analog of 16x16): row = lane&31, k = (lane>>5)*8 + j.
// ---------------------------------------------------------------------------
__global__ __launch_bounds__(256, 2) void attn_kernel(
    const __bf16* __restrict__ Qb, const __bf16* __restrict__ Kb,
    const __bf16* __restrict__ VTb, __bf16* __restrict__ Ob) {
  __shared__ __bf16 Ks[2][4096];   // [kv 64][dk 64], chunk-swizzled
  __shared__ __bf16 Vs[2][4096];   // [dk 64][kv 64], chunk-swizzled
  const int t = threadIdx.x, l = t & 63, w = t >> 6;
  const int q5 = l & 31, hi = l >> 5;
  const int bid = blockIdx.x;
  const int logical = (bid & 7) * 64 + (bid >> 3);  // XCD-cluster same-bh
  const int pj = logical & 7, bh = logical >> 3;
  const int bb = bh >> 4, h = bh & 15;
  const __bf16* Kbase = Kb  + (size_t)bh * 2048 * 64;
  const __bf16* Vbase = VTb + (size_t)bh * 64 * 2048;
  const __bf16* Qbase = Qb  + (size_t)bh * 2048 * 64;

  auto STAGEKV = [&](int buf, int kt) {
#pragma unroll
    for (int rep = 0; rep < 2; ++rep) {
      int c = w * 128 + rep * 64 + l;
      int row = c >> 3, cc = c & 7;
      int pc = (cc ^ (row & 7)) * 8;            // pre-swizzled source chunk
      gl_lds16(Kbase + (size_t)(kt * 64 + row) * 64 + pc,
               &Ks[buf][(w * 128 + rep * 64) * 8]);
      gl_lds16(Vbase + (size_t)row * 2048 + kt * 64 + pc,
               &Vs[buf][(w * 128 + rep * 64) * 8]);
    }
  };

  int cur = 0;
#pragma unroll 1
  for (int phase = 0; phase < 2; ++phase) {
    const int J = phase ? (15 - pj) : pj;       // 128-row q-block
    const int qloc = w * 32 + q5;
    const int qrow = J * 128 + qloc;

    bf16x8 qf[4];
#pragma unroll
    for (int ks = 0; ks < 4; ++ks)
      qf[ks] = *reinterpret_cast<const bf16x8*>(
          Qbase + (size_t)qrow * 64 + ks * 16 + hi * 8);

    f32x16 ot[2] = {};
    float lsum = 0.f;

    STAGEKV(cur, 0);
    __syncthreads();

    const int NT = 2 * J + 2;
    for (int kt = 0; kt < NT; ++kt) {
      if (kt + 1 < NT) STAGEKV(cur ^ 1, kt + 1);

      // ---- S^T = K x Q (two 32-kv blocks) ----
      f32x16 s[2] = {};
      {
        const char* kr0 = (const char*)&Ks[cur][q5 * 64];
        const char* kr1 = (const char*)&Ks[cur][(32 + q5) * 64];
        const int sz = (q5 & 7) << 4;           // rows q5, q5+32 share row&7
        __builtin_amdgcn_s_setprio(1);
#pragma unroll
        for (int ks = 0; ks < 4; ++ks) {
          bf16x8 kf0 = *reinterpret_cast<const bf16x8*>(kr0 + ((ks * 32 + hi * 16) ^ sz));
          bf16x8 kf1 = *reinterpret_cast<const bf16x8*>(kr1 + ((ks * 32 + hi * 16) ^ sz));
          s[0] = __builtin_amdgcn_mfma_f32_32x32x16_bf16(kf0, qf[ks], s[0], 0, 0, 0);
          s[1] = __builtin_amdgcn_mfma_f32_32x32x16_bf16(kf1, qf[ks], s[1], 0, 0, 0);
        }
        __builtin_amdgcn_s_setprio(0);
      }

      // ---- causal mask (last two tiles of this q-block) + exp2 + sum ----
      if (kt >= 2 * J) {
        const int doff = (kt - 2 * J) * 64;
#pragma unroll
        for (int r = 0; r < 16; ++r) {
          int kvloc = (r & 3) + 8 * (r >> 2) + 4 * hi;
          if (doff + kvloc > qloc)      s[0][r] = -INFINITY;
          if (doff + 32 + kvloc > qloc) s[1][r] = -INFINITY;
        }
      }
      float rs = 0.f;
#pragma unroll
      for (int kvb = 0; kvb < 2; ++kvb)
#pragma unroll
        for (int r = 0; r < 16; ++r) {
          float p = __builtin_amdgcn_exp2f(s[kvb][r]);
          s[kvb][r] = p;
          rs += p;
        }
      lsum += rs;

      // ---- build PV B-frags in-register (T12-style, shfl_xor(32)) ----
      // 16-kv block k: source s[k>>1], reg base rb=(k&1)*8.
      // own words = regs rb+4*hi+{0..3}; partner words = regs rb+4*(1-hi)+{0..3}.
      bf16x8 pb[4];
#pragma unroll
      for (int k = 0; k < 4; ++k) {
        const int rb = (k & 1) * 8;
        float o0, o1, o2, o3, e0, e1, e2, e3;
        if (k < 2) {
          o0 = s[0][rb + 4 * hi + 0]; o1 = s[0][rb + 4 * hi + 1];
          o2 = s[0][rb + 4 * hi + 2]; o3 = s[0][rb + 4 * hi + 3];
          e0 = s[0][rb + 4 * (1 - hi) + 0]; e1 = s[0][rb + 4 * (1 - hi) + 1];
          e2 = s[0][rb + 4 * (1 - hi) + 2]; e3 = s[0][rb + 4 * (1 - hi) + 3];
        } else {
          o0 = s[1][rb + 4 * hi + 0]; o1 = s[1][rb + 4 * hi + 1];
          o2 = s[1][rb + 4 * hi + 2]; o3 = s[1][rb + 4 * hi + 3];
          e0 = s[1][rb + 4 * (1 - hi) + 0]; e1 = s[1][rb + 4 * (1 - hi) + 1];
          e2 = s[1][rb + 4 * (1 - hi) + 2]; e3 = s[1][rb + 4 * (1 - hi) + 3];
        }
        unsigned ownA = pk2(o0, o1), ownB = pk2(o2, o3);
        unsigned sndA = pk2(e0, e1), sndB = pk2(e2, e3);
        unsigned gA = (unsigned)__shfl_xor((int)sndA, 32);
        unsigned gB = (unsigned)__shfl_xor((int)sndB, 32);
        union { unsigned u[4]; bf16x8 v; } z;
        z.u[0] = hi ? gA : ownA;
        z.u[1] = hi ? gB : ownB;
        z.u[2] = hi ? ownA : gA;
        z.u[3] = hi ? ownB : gB;
        pb[k] = z.v;
      }

      // ---- O^T += V^T x P (two 32-dk blocks) ----
      {
        const char* vr0 = (const char*)&Vs[cur][q5 * 64];
        const char* vr1 = (const char*)&Vs[cur][(32 + q5) * 64];
        const int sz = (q5 & 7) << 4;
        __builtin_amdgcn_s_setprio(1);
#pragma unroll
        for (int ks = 0; ks < 4; ++ks) {
          bf16x8 vf0 = *reinterpret_cast<const bf16x8*>(vr0 + ((ks * 32 + hi * 16) ^ sz));
          bf16x8 vf1 = *reinterpret_cast<const bf16x8*>(vr1 + ((ks * 32 + hi * 16) ^ sz));
          ot[0] = __builtin_amdgcn_mfma_f32_32x32x16_bf16(vf0, pb[ks], ot[0], 0, 0, 0);
          ot[1] = __builtin_amdgcn_mfma_f32_32x32x16_bf16(vf1, pb[ks], ot[1], 0, 0, 0);
        }
        __builtin_amdgcn_s_setprio(0);
      }
      __syncthreads();   // drains vmcnt(0): next buffer staged + reads done
      cur ^= 1;
    }

    // ---- normalize + write O (lane owns q-col q5; dk from reg map) ----
    lsum += __shfl_xor(lsum, 32);
    const float rl = 1.f / lsum;
#pragma unroll
    for (int dkb = 0; dkb < 2; ++dkb)
#pragma unroll
      for (int rq = 0; rq < 4; ++rq) {
        bf16x4 ok;
        ok[0] = (__bf16)(ot[dkb][rq * 4 + 0] * rl);
        ok[1] = (__bf16)(ot[dkb][rq * 4 + 1] * rl);
        ok[2] = (__bf16)(ot[dkb][rq * 4 + 2] * rl);
        ok[3] = (__bf16)(ot[dkb][rq * 4 + 3] * rl);
        int dk = dkb * 32 + rq * 8 + 4 * hi;
        *reinterpret_cast<bf16x4*>(
            &Ob[((size_t)(bb * 2048 + qrow)) * 1024 + h * 64 + dk]) = ok;
      }
  }
}

// ---------------------------------------------------------------------------
extern "C" void kernel_launch(void* const* d_in, const int* in_sizes, int n_in,
                              void* d_out, int out_size, void* d_ws, size_t ws_size,
                              hipStream_t stream) {
  const float* x      = (const float*)d_in[0];
  const float* w_qkv  = (const float*)d_in[2];
  const float* w_proj = (const float*)d_in[3];
  float* out = (float*)d_out;

  char* ws = (char*)d_ws;
  __bf16* wt_qkv  = (__bf16*)(ws);                               // 6291456 B
  __bf16* wt_proj = (__bf16*)(ws + 6291456);                     // 2097152 B
  __bf16* Qb      = (__bf16*)(ws + 8388608);                     // 16 MB each
  __bf16* Kb      = (__bf16*)(ws + 8388608 + 16777216);
  __bf16* VTb     = (__bf16*)(ws + 8388608 + 2 * 16777216);
  __bf16* Ob      = (__bf16*)(ws + 8388608 + 3 * 16777216);
  __bf16* Xb      = Ob;  // alias: Xb consumed by qkv_gemm before attn writes Ob

  prep_kernel<<<5120, 256, 0, stream>>>(x, Xb, w_qkv, wt_qkv, w_proj, wt_proj);
  qkv_gemm<<<1024, 256, 0, stream>>>(Xb, wt_qkv, Qb, Kb, VTb);
  attn_kernel<<<512, 256, 0, stream>>>(Qb, Kb, VTb, Ob);
  proj_gemm<<<512, 256, 0, stream>>>(Ob, wt_proj, out);
}

// Round 13
// 158.415 us; speedup vs baseline: 1.5797x; 1.5797x over previous
//
#include <hip/hip_runtime.h>
#include <hip/hip_bf16.h>
#include <stdint.h>

typedef __bf16 bf16x8 __attribute__((ext_vector_type(8)));
typedef __bf16 bf16x4 __attribute__((ext_vector_type(4)));
typedef float  f32x4  __attribute__((ext_vector_type(4)));

__device__ __forceinline__ void gl_lds16(const void* g, void* l) {
  __builtin_amdgcn_global_load_lds(
      (const __attribute__((address_space(1))) unsigned int*)g,
      (__attribute__((address_space(3))) unsigned int*)l, 16, 0, 0);
}

// ---------------------------------------------------------------------------
// Merged prep: X fp32->bf16 convert (blocks 0..4095), W_qkv transpose-convert
// (4096..4863), W_proj transpose-convert (4864..5119).
// ---------------------------------------------------------------------------
__global__ __launch_bounds__(256) void prep_kernel(
    const float* __restrict__ x, __bf16* __restrict__ Xb,
    const float* __restrict__ w_qkv, __bf16* __restrict__ wt_qkv,
    const float* __restrict__ w_proj, __bf16* __restrict__ wt_proj) {
  __shared__ __bf16 tile[64][65];
  const int bid = blockIdx.x, t = threadIdx.x;
  if (bid < 4096) {
    const size_t i = ((size_t)bid * 256 + t) * 8;
    float4 v0 = *reinterpret_cast<const float4*>(x + i);
    float4 v1 = *reinterpret_cast<const float4*>(x + i + 4);
    bf16x8 o;
    o[0] = (__bf16)v0.x; o[1] = (__bf16)v0.y; o[2] = (__bf16)v0.z; o[3] = (__bf16)v0.w;
    o[4] = (__bf16)v1.x; o[5] = (__bf16)v1.y; o[6] = (__bf16)v1.z; o[7] = (__bf16)v1.w;
    *reinterpret_cast<bf16x8*>(Xb + i) = o;
    return;
  }
  const float* src; __bf16* dst; int K, N, bx, by;
  if (bid < 4864) {
    int idx = bid - 4096;                // w_qkv: [1024][3072] -> [3072][1024]
    src = w_qkv; dst = wt_qkv; K = 1024; N = 3072;
    bx = idx % 48; by = idx / 48;
  } else {
    int idx = bid - 4864;                // w_proj: [1024][1024] -> [1024][1024]
    src = w_proj; dst = wt_proj; K = 1024; N = 1024;
    bx = idx & 15; by = idx >> 4;
  }
  const int n0 = bx * 64, k0 = by * 64;
#pragma unroll
  for (int e = 0; e < 16; ++e) {
    int idx = e * 256 + t;
    int kk = idx >> 6, nn = idx & 63;
    tile[nn][kk] = (__bf16)src[(size_t)(k0 + kk) * N + n0 + nn];
  }
  __syncthreads();
#pragma unroll
  for (int e = 0; e < 16; ++e) {
    int idx = e * 256 + t;
    int nn = idx >> 6, kk = idx & 63;
    dst[(size_t)(n0 + nn) * K + k0 + kk] = tile[nn][kk];
  }
}

// ---------------------------------------------------------------------------
// R8 triple-buffered counted-vmcnt GEMM core (measured best), with the
// R10-verified conflict-free swizzle: 16B slot s at row r holds global
// slot s ^ ((r>>1)&3)  [measured 0 LDS bank conflicts vs 5.77M for the
// old (r&3)^((r>>2)&3)].  Fragment rows ≡ lr (mod 16) -> read XOR is the
// wave-uniform (lr>>1)&3 for both A and B at NFRAG in {2,3}.
// BM=128, BN=NFRAG*64, BK=32, 256 thr = 4 waves.
// ---------------------------------------------------------------------------
template <int NFRAG>
__device__ __forceinline__ void gemm_core_1024(
    const __bf16* __restrict__ Ag, const __bf16* __restrict__ Bg,
    int m0, int n0, __bf16* lds, f32x4 (&acc)[8][NFRAG]) {
  constexpr int BUFSZ = 4096 + NFRAG * 2048;
  const int tid = threadIdx.x;
  const int wv = tid >> 6, l = tid & 63, g = l >> 4, lr = l & 15;
  const int rsw = (lr >> 1) & 3;                 // read-side XOR (wave-uniform)

  int arow[2], acol[2], brow[NFRAG], bcol[NFRAG];
#pragma unroll
  for (int e = 0; e < 2; ++e) {
    int c = e * 256 + tid, row = c >> 2, slot = c & 3;
    arow[e] = row;
    acol[e] = (slot ^ ((row >> 1) & 3)) * 8;     // pre-swizzled source col
  }
#pragma unroll
  for (int e = 0; e < NFRAG; ++e) {
    int c = e * 256 + tid, row = c >> 2, slot = c & 3;
    brow[e] = row;
    bcol[e] = (slot ^ ((row >> 1) & 3)) * 8;
  }

  auto STAGE = [&](int bufb, int t) {
    const int kb = t * 32;
#pragma unroll
    for (int e = 0; e < 2; ++e)
      gl_lds16(Ag + (size_t)(m0 + arow[e]) * 1024 + kb + acol[e],
               lds + bufb + (e * 256 + wv * 64) * 8);
#pragma unroll
    for (int e = 0; e < NFRAG; ++e)
      gl_lds16(Bg + (size_t)(n0 + brow[e]) * 1024 + kb + bcol[e],
               lds + bufb + 4096 + (e * 256 + wv * 64) * 8);
  };

  int cur = 0, nx = BUFSZ, nn = 2 * BUFSZ;
  STAGE(cur, 0);
  STAGE(nx, 1);

#pragma unroll 1
  for (int t = 0; t < 32; ++t) {
    if (t < 31) {
      if constexpr (NFRAG == 3) asm volatile("s_waitcnt vmcnt(5)" ::: "memory");
      else                      asm volatile("s_waitcnt vmcnt(4)" ::: "memory");
    } else {
      asm volatile("s_waitcnt vmcnt(0)" ::: "memory");
    }
    __builtin_amdgcn_s_barrier();
    __builtin_amdgcn_sched_barrier(0);
    if (t + 2 < 32) STAGE(nn, t + 2);   // buf of tile t-1: safe post-barrier

    const char* Ab = (const char*)(lds + cur);
    const char* Bb = (const char*)(lds + cur + 4096);
    bf16x8 a[8], b[NFRAG];
#pragma unroll
    for (int mf = 0; mf < 8; ++mf)
      a[mf] = *reinterpret_cast<const bf16x8*>(
          Ab + (mf * 16 + lr) * 64 + ((g ^ rsw) << 4));
#pragma unroll
    for (int nf = 0; nf < NFRAG; ++nf)
      b[nf] = *reinterpret_cast<const bf16x8*>(
          Bb + (wv * NFRAG * 16 + nf * 16 + lr) * 64 + ((g ^ rsw) << 4));
    __builtin_amdgcn_s_setprio(1);
#pragma unroll
    for (int mf = 0; mf < 8; ++mf)
#pragma unroll
      for (int nf = 0; nf < NFRAG; ++nf)
        acc[mf][nf] = __builtin_amdgcn_mfma_f32_16x16x32_bf16(
            a[mf], b[nf], acc[mf][nf], 0, 0, 0);
    __builtin_amdgcn_s_setprio(0);

    int tmp = cur; cur = nx; nx = nn; nn = tmp;
  }
}

// ---------------------------------------------------------------------------
// QKV GEMM (R8 config): grid 1024 = 64 rb x 16 cb, BM=128 BN=192 -> exactly
// 2 full rounds at 2 blocks/CU. Fragments resolved per wave-uniform base.
// ---------------------------------------------------------------------------
__global__ __launch_bounds__(256, 2) void qkv_gemm(
    const __bf16* __restrict__ Xb, const __bf16* __restrict__ WT,
    __bf16* __restrict__ Qb, __bf16* __restrict__ Kb, __bf16* __restrict__ Vb) {
  __shared__ __bf16 lds[30720];
  const int lin = blockIdx.x;
  const int sw = (lin & 7) * 128 + (lin >> 3);  // T1 bijective (1024 % 8 == 0)
  const int rb = sw >> 4, cb = sw & 15;
  const int m0 = rb * 128, n0 = cb * 192;

  f32x4 acc[8][3] = {};
  gemm_core_1024<3>(Xb, WT, m0, n0, lds, acc);

  const int tid = threadIdx.x, wv = tid >> 6, l = tid & 63, g = l >> 4, lr = l & 15;
#pragma unroll
  for (int mf = 0; mf < 8; ++mf)
#pragma unroll
    for (int nf = 0; nf < 3; ++nf) {
      int m_ = m0 + mf * 16 + g * 4;
      int nb = n0 + wv * 48 + nf * 16;          // wave-uniform fragment base
      int which = nb >> 10, hc = nb & 1023;
      int hh = hc >> 6, dk0 = hc & 63;          // dk0+lr < 64 (16 | boundaries)
      int bbv = m_ >> 11, tt = m_ & 2047;
      if (which == 2) {
        bf16x4 vk;
        vk[0] = (__bf16)acc[mf][nf][0]; vk[1] = (__bf16)acc[mf][nf][1];
        vk[2] = (__bf16)acc[mf][nf][2]; vk[3] = (__bf16)acc[mf][nf][3];
        *reinterpret_cast<bf16x4*>(
            &Vb[((size_t)(bbv * 16 + hh) * 64 + dk0 + lr) * 2048 + tt]) = vk;
      } else if (which == 0) {
#pragma unroll
        for (int j = 0; j < 4; ++j)
          Qb[(((size_t)(bbv * 16 + hh)) * 2048 + tt + j) * 64 + dk0 + lr] =
              (__bf16)(acc[mf][nf][j] * 0.18033688f);  // 0.125*log2(e)
      } else {
#pragma unroll
        for (int j = 0; j < 4; ++j)
          Kb[(((size_t)(bbv * 16 + hh)) * 2048 + tt + j) * 64 + dk0 + lr] =
              (__bf16)acc[mf][nf][j];
      }
    }
}

// ---------------------------------------------------------------------------
// Proj GEMM (R8 config): grid 512 = 64 rb x 8 cb, BM=128 BN=128 -> one full
// round at 2 blocks/CU (8 waves/CU). Out fp32.
// ---------------------------------------------------------------------------
__global__ __launch_bounds__(256, 2) void proj_gemm(
    const __bf16* __restrict__ A, const __bf16* __restrict__ WT,
    float* __restrict__ Out) {
  __shared__ __bf16 lds[24576];
  const int lin = blockIdx.x;
  const int sw = (lin & 7) * 64 + (lin >> 3);   // T1 bijective (512 % 8 == 0)
  const int rb = sw >> 3, cb = sw & 7;
  const int m0 = rb * 128, n0 = cb * 128;

  f32x4 acc[8][2] = {};
  gemm_core_1024<2>(A, WT, m0, n0, lds, acc);

  const int tid = threadIdx.x, wv = tid >> 6, l = tid & 63, g = l >> 4, lr = l & 15;
#pragma unroll
  for (int mf = 0; mf < 8; ++mf)
#pragma unroll
    for (int nf = 0; nf < 2; ++nf) {
      int m_ = m0 + mf * 16 + g * 4;
      int n  = n0 + wv * 32 + nf * 16 + lr;
#pragma unroll
      for (int j = 0; j < 4; ++j)
        Out[(size_t)(m_ + j) * 1024 + n] = acc[mf][nf][j];
    }
}

// ---------------------------------------------------------------------------
// Causal flash attention, DUAL-Q per block (R6-R8 measured best, ~56 us).
// ---------------------------------------------------------------------------
__global__ __launch_bounds__(256, 2) void attn_kernel(
    const __bf16* __restrict__ Qb, const __bf16* __restrict__ Kb,
    const __bf16* __restrict__ VTb, __bf16* __restrict__ Ob) {
  __shared__ __bf16 Ks[2][4096];
  __shared__ __bf16 Vs[2][4096];
  __shared__ __bf16 PlA[4][1024];
  __shared__ __bf16 PlB[4][1024];
  const int t = threadIdx.x, l = t & 63, w = t >> 6;
  const int g = l >> 4, lr = l & 15;
  const int bid = blockIdx.x;
  const int logical = (bid & 7) * 64 + (bid >> 3);
  const int pj = logical & 7, bh = logical >> 3;
  const int bb = bh >> 4, h = bh & 15;
  const __bf16* Kbase = Kb  + (size_t)bh * 2048 * 64;
  const __bf16* Vbase = VTb + (size_t)bh * 64 * 2048;
  const __bf16* Qbase = Qb  + (size_t)bh * 2048 * 64;
  const int swz = (lr & 7) << 4;

  int cur = 0;
#pragma unroll 1
  for (int phase = 0; phase < 2; ++phase) {
    const int J = phase ? (15 - pj) : pj;
    const int qtA = 2 * J, qtB = 2 * J + 1;
    const int qrowA = J * 128 + w * 16 + lr;
    const int qrowB = qrowA + 64;
    const bf16x8 qfA0 = *reinterpret_cast<const bf16x8*>(Qbase + (size_t)qrowA * 64 + g * 8);
    const bf16x8 qfA1 = *reinterpret_cast<const bf16x8*>(Qbase + (size_t)qrowA * 64 + 32 + g * 8);
    const bf16x8 qfB0 = *reinterpret_cast<const bf16x8*>(Qbase + (size_t)qrowB * 64 + g * 8);
    const bf16x8 qfB1 = *reinterpret_cast<const bf16x8*>(Qbase + (size_t)qrowB * 64 + 32 + g * 8);

    f32x4 otA[4] = {}, otB[4] = {};
    float lsA = 0.f, lsB = 0.f;

#pragma unroll
    for (int rep = 0; rep < 2; ++rep) {
      int c = w * 128 + rep * 64 + l;
      int row = c >> 3, cc = c & 7;
      int pc = (cc ^ (row & 7)) * 8;
      gl_lds16(Kbase + (size_t)row * 64 + pc, &Ks[cur][(w * 128 + rep * 64) * 8]);
      gl_lds16(Vbase + (size_t)row * 2048 + pc, &Vs[cur][(w * 128 + rep * 64) * 8]);
    }
    __syncthreads();

    for (int kt = 0; kt <= qtB; ++kt) {
      const bool aAct = (kt <= qtA);
      if (kt < qtB) {
        const int nv0 = (kt + 1) * 64;
#pragma unroll
        for (int rep = 0; rep < 2; ++rep) {
          int c = w * 128 + rep * 64 + l;
          int row = c >> 3, cc = c & 7;
          int pc = (cc ^ (row & 7)) * 8;
          gl_lds16(Kbase + (size_t)(nv0 + row) * 64 + pc,
                   &Ks[cur ^ 1][(w * 128 + rep * 64) * 8]);
          gl_lds16(Vbase + (size_t)row * 2048 + nv0 + pc,
                   &Vs[cur ^ 1][(w * 128 + rep * 64) * 8]);
        }
      }
      bf16x8 klo[4], khi[4];
#pragma unroll
      for (int nf = 0; nf < 4; ++nf) {
        const char* kr = (const char*)&Ks[cur][(nf * 16 + lr) * 64];
        klo[nf] = *reinterpret_cast<const bf16x8*>(kr + ((g * 16) ^ swz));
        khi[nf] = *reinterpret_cast<const bf16x8*>(kr + ((64 + g * 16) ^ swz));
      }
      f32x4 stA[4], stB[4];
      __builtin_amdgcn_s_setprio(1);
#pragma unroll
      for (int nf = 0; nf < 4; ++nf) {
        f32x4 z = {};
        z = __builtin_amdgcn_mfma_f32_16x16x32_bf16(klo[nf], qfB0, z, 0, 0, 0);
        stB[nf] = __builtin_amdgcn_mfma_f32_16x16x32_bf16(khi[nf], qfB1, z, 0, 0, 0);
      }
      if (aAct) {
#pragma unroll
        for (int nf = 0; nf < 4; ++nf) {
          f32x4 z = {};
          z = __builtin_amdgcn_mfma_f32_16x16x32_bf16(klo[nf], qfA0, z, 0, 0, 0);
          stA[nf] = __builtin_amdgcn_mfma_f32_16x16x32_bf16(khi[nf], qfA1, z, 0, 0, 0);
        }
      }
      __builtin_amdgcn_s_setprio(0);
      if (kt == qtB) {
#pragma unroll
        for (int nf = 0; nf < 4; ++nf)
#pragma unroll
          for (int j = 0; j < 4; ++j)
            if (nf * 16 + g * 4 + j > w * 16 + lr) stB[nf][j] = -INFINITY;
      }
      if (aAct && kt == qtA) {
#pragma unroll
        for (int nf = 0; nf < 4; ++nf)
#pragma unroll
          for (int j = 0; j < 4; ++j)
            if (nf * 16 + g * 4 + j > w * 16 + lr) stA[nf][j] = -INFINITY;
      }
      {
        float rs = 0.f;
        char* prow = (char*)&PlB[w][lr * 64];
#pragma unroll
        for (int nf = 0; nf < 4; ++nf) {
#pragma unroll
          for (int j = 0; j < 4; ++j) {
            float p = __builtin_amdgcn_exp2f(stB[nf][j]);
            stB[nf][j] = p;
            rs += p;
          }
          bf16x4 pk;
          pk[0] = (__bf16)stB[nf][0]; pk[1] = (__bf16)stB[nf][1];
          pk[2] = (__bf16)stB[nf][2]; pk[3] = (__bf16)stB[nf][3];
          *reinterpret_cast<bf16x4*>(prow + ((nf * 32 + g * 8) ^ swz)) = pk;
        }
        lsB += rs;
      }
      if (aAct) {
        float rs = 0.f;
        char* prow = (char*)&PlA[w][lr * 64];
#pragma unroll
        for (int nf = 0; nf < 4; ++nf) {
#pragma unroll
          for (int j = 0; j < 4; ++j) {
            float p = __builtin_amdgcn_exp2f(stA[nf][j]);
            stA[nf][j] = p;
            rs += p;
          }
          bf16x4 pk;
          pk[0] = (__bf16)stA[nf][0]; pk[1] = (__bf16)stA[nf][1];
          pk[2] = (__bf16)stA[nf][2]; pk[3] = (__bf16)stA[nf][3];
          *reinterpret_cast<bf16x4*>(prow + ((nf * 32 + g * 8) ^ swz)) = pk;
        }
        lsA += rs;
      }
      {
        bf16x8 vlo[4], vhi[4];
#pragma unroll
        for (int nf = 0; nf < 4; ++nf) {
          const char* vr = (const char*)&Vs[cur][(nf * 16 + lr) * 64];
          vlo[nf] = *reinterpret_cast<const bf16x8*>(vr + ((g * 16) ^ swz));
          vhi[nf] = *reinterpret_cast<const bf16x8*>(vr + ((64 + g * 16) ^ swz));
        }
        const char* prB = (const char*)&PlB[w][lr * 64];
        bf16x8 pb0 = *reinterpret_cast<const bf16x8*>(prB + ((g * 16) ^ swz));
        bf16x8 pb1 = *reinterpret_cast<const bf16x8*>(prB + ((64 + g * 16) ^ swz));
        __builtin_amdgcn_s_setprio(1);
#pragma unroll
        for (int nf = 0; nf < 4; ++nf) {
          otB[nf] = __builtin_amdgcn_mfma_f32_16x16x32_bf16(vlo[nf], pb0, otB[nf], 0, 0, 0);
          otB[nf] = __builtin_amdgcn_mfma_f32_16x16x32_bf16(vhi[nf], pb1, otB[nf], 0, 0, 0);
        }
        __builtin_amdgcn_s_setprio(0);
        if (aAct) {
          const char* prA = (const char*)&PlA[w][lr * 64];
          bf16x8 pa0 = *reinterpret_cast<const bf16x8*>(prA + ((g * 16) ^ swz));
          bf16x8 pa1 = *reinterpret_cast<const bf16x8*>(prA + ((64 + g * 16) ^ swz));
          __builtin_amdgcn_s_setprio(1);
#pragma unroll
          for (int nf = 0; nf < 4; ++nf) {
            otA[nf] = __builtin_amdgcn_mfma_f32_16x16x32_bf16(vlo[nf], pa0, otA[nf], 0, 0, 0);
            otA[nf] = __builtin_amdgcn_mfma_f32_16x16x32_bf16(vhi[nf], pa1, otA[nf], 0, 0, 0);
          }
          __builtin_amdgcn_s_setprio(0);
        }
      }
      __syncthreads();
      cur ^= 1;
    }

    lsA += __shfl_xor(lsA, 16); lsA += __shfl_xor(lsA, 32);
    lsB += __shfl_xor(lsB, 16); lsB += __shfl_xor(lsB, 32);
    const float rlA = 1.f / lsA, rlB = 1.f / lsB;
#pragma unroll
    for (int nf = 0; nf < 4; ++nf) {
      bf16x4 ok;
      ok[0] = (__bf16)(otA[nf][0] * rlA); ok[1] = (__bf16)(otA[nf][1] * rlA);
      ok[2] = (__bf16)(otA[nf][2] * rlA); ok[3] = (__bf16)(otA[nf][3] * rlA);
      *reinterpret_cast<bf16x4*>(
          &Ob[((size_t)(bb * 2048 + qrowA)) * 1024 + h * 64 + nf * 16 + g * 4]) = ok;
      bf16x4 ok2;
      ok2[0] = (__bf16)(otB[nf][0] * rlB); ok2[1] = (__bf16)(otB[nf][1] * rlB);
      ok2[2] = (__bf16)(otB[nf][2] * rlB); ok2[3] = (__bf16)(otB[nf][3] * rlB);
      *reinterpret_cast<bf16x4*>(
          &Ob[((size_t)(bb * 2048 + qrowB)) * 1024 + h * 64 + nf * 16 + g * 4]) = ok2;
    }
  }
}

// ---------------------------------------------------------------------------
extern "C" void kernel_launch(void* const* d_in, const int* in_sizes, int n_in,
                              void* d_out, int out_size, void* d_ws, size_t ws_size,
                              hipStream_t stream) {
  const float* x      = (const float*)d_in[0];
  const float* w_qkv  = (const float*)d_in[2];
  const float* w_proj = (const float*)d_in[3];
  float* out = (float*)d_out;

  char* ws = (char*)d_ws;
  __bf16* wt_qkv  = (__bf16*)(ws);                               // 6291456 B
  __bf16* wt_proj = (__bf16*)(ws + 6291456);                     // 2097152 B
  __bf16* Qb      = (__bf16*)(ws + 8388608);                     // 16 MB each
  __bf16* Kb      = (__bf16*)(ws + 8388608 + 16777216);
  __bf16* VTb     = (__bf16*)(ws + 8388608 + 2 * 16777216);
  __bf16* Ob      = (__bf16*)(ws + 8388608 + 3 * 16777216);
  __bf16* Xb      = Ob;  // alias: Xb consumed by qkv_gemm before attn writes Ob

  prep_kernel<<<5120, 256, 0, stream>>>(x, Xb, w_qkv, wt_qkv, w_proj, wt_proj);
  qkv_gemm<<<1024, 256, 0, stream>>>(Xb, wt_qkv, Qb, Kb, VTb);
  attn_kernel<<<512, 256, 0, stream>>>(Qb, Kb, VTb, Ob);
  proj_gemm<<<512, 256, 0, stream>>>(Ob, wt_proj, out);
}